// Round 11
// baseline (452.634 us; speedup 1.0000x reference)
//
#include <hip/hip_runtime.h>
#include <hip/hip_bf16.h>
#include <math.h>

#define H 1024
#define F 3584
#define F2 7168
#define NE 8
#define T 1024

typedef __attribute__((ext_vector_type(4))) float f32x4;
typedef __attribute__((ext_vector_type(8))) short bf16x8;
typedef __attribute__((ext_vector_type(4))) unsigned u32x4;

__device__ inline short f2bf(float f) {
  union { float f; unsigned u; } v; v.f = f;
  unsigned r = (v.u + 0x7FFFu + ((v.u >> 16) & 1u)) >> 16;
  return (short)r;
}

__device__ inline unsigned pkbf(float a, float b) {
  unsigned r;
  asm("v_cvt_pk_bf16_f32 %0, %1, %2" : "=v"(r) : "v"(a), "v"(b));
  return r;
}

#define MFMA16(af, bf, c) __builtin_amdgcn_mfma_f32_16x16x32_bf16((af), (bf), (c), 0, 0, 0)

// load 8 fp32 at element stride st, convert to bf16x8 (R7/R10-proven shape)
__device__ inline bf16x8 ldcvt(const float* p, int st) {
  float f0 = p[0],      f1 = p[st],     f2 = p[2 * st], f3 = p[3 * st];
  float f4 = p[4 * st], f5 = p[5 * st], f6 = p[6 * st], f7 = p[7 * st];
  union { u32x4 u; bf16x8 h; } cv;
  cv.u[0] = pkbf(f0, f1); cv.u[1] = pkbf(f2, f3);
  cv.u[2] = pkbf(f4, f5); cv.u[3] = pkbf(f6, f7);
  return cv.h;
}

// async global->LDS, 16B per lane. LDS dest = wave-uniform base + lane*16.
__device__ inline void gload16(const void* g, void* l) {
  __builtin_amdgcn_global_load_lds(
      (const __attribute__((address_space(1))) void*)g,
      (__attribute__((address_space(3))) void*)l, 16, 0, 0);
}

// ---------------- x -> bf16 prepass ----------------
__global__ __launch_bounds__(256) void cvtx_k(
    const float* __restrict__ x, unsigned short* __restrict__ xb)
{
  int i = (blockIdx.x * 256 + threadIdx.x) * 8;
  f32x4 a = *(const f32x4*)(x + i);
  f32x4 b = *(const f32x4*)(x + i + 4);
  u32x4 o;
  o[0] = pkbf(a[0], a[1]); o[1] = pkbf(a[2], a[3]);
  o[2] = pkbf(b[0], b[1]); o[3] = pkbf(b[2], b[3]);
  *(u32x4*)(xb + i) = o;
}

// ---------------- router: fp64 logits, top-2 ----------------
__global__ __launch_bounds__(64) void router_k(
    const float* __restrict__ x, const float* __restrict__ gw,
    float* __restrict__ logits, int* __restrict__ cnt,
    int* __restrict__ tok_e, int* __restrict__ tok_r, float* __restrict__ tok_w)
{
  int t = blockIdx.x, l = threadIdx.x;
  const float* xr = x + (size_t)t * H;
  double acc[NE];
  #pragma unroll
  for (int e = 0; e < NE; ++e) acc[e] = 0.0;
  for (int j = 0; j < H / 64; ++j) {
    int h = j * 64 + l;
    float xv = xr[h];
    #pragma unroll
    for (int e = 0; e < NE; ++e) acc[e] += (double)xv * (double)gw[e * H + h];
  }
  #pragma unroll
  for (int off = 32; off >= 1; off >>= 1) {
    #pragma unroll
    for (int e = 0; e < NE; ++e) acc[e] += __shfl_down(acc[e], off, 64);
  }
  if (l == 0) {
    float lg[NE];
    #pragma unroll
    for (int e = 0; e < NE; ++e) { lg[e] = (float)acc[e]; logits[t * NE + e] = lg[e]; }
    int i0 = 0;
    for (int e = 1; e < NE; ++e) if (lg[e] > lg[i0]) i0 = e;
    int i1 = (i0 == 0) ? 1 : 0;
    for (int e = 0; e < NE; ++e) if (e != i0 && lg[e] > lg[i1]) i1 = e;
    float w0 = 1.f / (1.f + expf(lg[i1] - lg[i0]));
    float w1 = 1.f / (1.f + expf(lg[i0] - lg[i1]));
    int r0 = atomicAdd(&cnt[i0], 1);
    int r1 = atomicAdd(&cnt[i1], 1);
    tok_e[2 * t] = i0;     tok_r[2 * t] = r0;     tok_w[2 * t] = w0;
    tok_e[2 * t + 1] = i1; tok_r[2 * t + 1] = r1; tok_w[2 * t + 1] = w1;
  }
}

// ---------------- scan + gather list ----------------
__global__ __launch_bounds__(1024) void build_k(
    const int* __restrict__ cnt, int* __restrict__ base,
    const int* __restrict__ tok_e, const int* __restrict__ tok_r,
    const float* __restrict__ tok_w, int* __restrict__ gtok, float* __restrict__ gws)
{
  __shared__ int sb[NE];
  if (threadIdx.x == 0) {
    int s = 0;
    for (int e = 0; e < NE; ++e) { sb[e] = s; base[e] = s; s += cnt[e]; }
  }
  __syncthreads();
  int t = threadIdx.x;
  #pragma unroll
  for (int k = 0; k < 2; ++k) {
    int e = tok_e[2 * t + k];
    int slot = sb[e] + tok_r[2 * t + k];
    gtok[slot] = t;
    gws[slot] = tok_w[2 * t + k];
  }
}

// ---------------- ffn1: M=128, N=256 (128g+128u), BK=32 ----------------
// B: gload_lds fp32, double-buffered, counted vmcnt. 2-way bank swizzle:
// src chunk ^ swz(wv), read byte ^ (swz(lg)<<4), swz(v)=((v&1)<<2)|(v>>1).
// A: direct-global bf16 fragment loads (xb prepass). 32 MFMA/wave/phase.
__global__ __launch_bounds__(256, 2) void ffn1_k(
    const unsigned short* __restrict__ xb, const float* __restrict__ wgu,
    const int* __restrict__ cnt, const int* __restrict__ base,
    const int* __restrict__ gtok, unsigned short* __restrict__ act)
{
  // 1792 blocks = 8 XCD * 224 (e = xcd); per XCD: 28 p * 8 mB, mB fastest
  int e = blockIdx.x & 7;
  int idx = blockIdx.x >> 3;          // 0..223
  int mB = idx & 7;
  int p = idx >> 3;                   // 0..27
  int n = cnt[e];
  int m0 = mB * 128;
  if (m0 >= n) return;
  int sb = base[e];
  int tid = threadIdx.x;
  int wv = tid >> 6, lane = tid & 63, lr = lane & 15, lg = lane >> 4;

  __shared__ __align__(16) char smem[65536];
  char* sB0 = smem;
  char* sB1 = smem + 32768;

  // B staging: wave wv stages k-rows wv*8+j (j=0..7), 1KB/row, chunk pre-swizzled
  int swzv = ((wv & 1) << 2) | (wv >> 1);
  int bchunk = lane ^ swzv;           // bijective within 64 chunks
  int tc = bchunk * 4;
  int gc = (tc < 128) ? (p * 128 + tc) : (F + p * 128 + (tc - 128));
  const float* Bsrc = wgu + (size_t)e * H * F2 + (size_t)(wv * 8) * F2 + gc;

  // B read offsets (byte, within k-row): 2-way bank-aliased
  int swzl = ((lg & 1) << 2) | (lg >> 1);
  int rb[4];
  #pragma unroll
  for (int cf = 0; cf < 4; ++cf) {
    int col = wv * 32 + (cf & 1) * 16 + ((cf >> 1) ? 128 : 0) + lr;
    rb[cf] = (col * 4) ^ (swzl << 4);
  }
  const int rowbase = lg * 8 * 1024;  // first of 8 k-rows this lane reads

  // A per-lane row pointers (token gather, clamped): 8 m-frags, direct global bf16
  const unsigned short* ax[8];
  #pragma unroll
  for (int mf = 0; mf < 8; ++mf) {
    int sl = m0 + mf * 16 + lr; if (sl >= n) sl = n - 1;
    ax[mf] = xb + (size_t)gtok[sb + sl] * H + lg * 8;
  }

  f32x4 acc[8][4];
  #pragma unroll
  for (int mf = 0; mf < 8; ++mf)
    #pragma unroll
    for (int cf = 0; cf < 4; ++cf) acc[mf][cf] = (f32x4)0.f;

#define ISSUE1(S, buf) { \
    const float* bs_ = Bsrc + (size_t)(S) * 32 * F2; \
    _Pragma("unroll") for (int j = 0; j < 8; ++j) \
      gload16(bs_ + (size_t)j * F2, (buf) + (wv * 8 + j) * 1024); }

  ISSUE1(0, sB0);
  ISSUE1(1, sB1);

  for (int s = 0; s < 32; ++s) {
    char* cB = (s & 1) ? sB1 : sB0;
    if (s < 31) { asm volatile("s_waitcnt vmcnt(8)" ::: "memory"); }
    else        { asm volatile("s_waitcnt vmcnt(0)" ::: "memory"); }
    __builtin_amdgcn_s_barrier();
    asm volatile("" ::: "memory");

    bf16x8 b0 = ldcvt((const float*)(cB + rowbase + rb[0]), 256);
    bf16x8 b1 = ldcvt((const float*)(cB + rowbase + rb[1]), 256);
    bf16x8 b2 = ldcvt((const float*)(cB + rowbase + rb[2]), 256);
    bf16x8 b3 = ldcvt((const float*)(cB + rowbase + rb[3]), 256);
    #pragma unroll
    for (int mf = 0; mf < 8; ++mf) {
      bf16x8 af = *(const bf16x8*)(ax[mf] + s * 32);
      acc[mf][0] = MFMA16(af, b0, acc[mf][0]);
      acc[mf][1] = MFMA16(af, b1, acc[mf][1]);
      acc[mf][2] = MFMA16(af, b2, acc[mf][2]);
      acc[mf][3] = MFMA16(af, b3, acc[mf][3]);
    }
    asm volatile("s_waitcnt lgkmcnt(0)" ::: "memory");
    __builtin_amdgcn_s_barrier();
    asm volatile("" ::: "memory");
    if (s + 2 < 32) { ISSUE1(s + 2, cB); }
  }
#undef ISSUE1

  // epilogue: silu(gate)*up; gate cf 0..1, up cf 2..3
  #pragma unroll
  for (int mf = 0; mf < 8; ++mf) {
    #pragma unroll
    for (int g = 0; g < 2; ++g) {
      int fcol = p * 128 + wv * 32 + g * 16 + lr;
      #pragma unroll
      for (int r = 0; r < 4; ++r) {
        int sl = m0 + mf * 16 + lg * 4 + r;
        if (sl < n) {
          float gg = acc[mf][g][r], u = acc[mf][g + 2][r];
          act[(size_t)(sb + sl) * F + fcol] = (unsigned short)f2bf(gg / (1.f + expf(-gg)) * u);
        }
      }
    }
  }
}

// ---------------- ffn2: M=128, N=128, BK=32, K-split x2 (56 phases) ----------------
// Same structure: B gload_lds dbuf (512B rows), A = act bf16 direct global.
__global__ __launch_bounds__(256, 2) void ffn2_k(
    const unsigned short* __restrict__ act, const float* __restrict__ wd,
    const int* __restrict__ cnt, const int* __restrict__ base,
    const int* __restrict__ gtok, const float* __restrict__ gws,
    float* __restrict__ out)
{
  // 1024 blocks = 8 XCD * 128 (e = xcd); per XCD: 8 p * 2 kh * 8 mB, mB fastest
  int e = blockIdx.x & 7;
  int idx = blockIdx.x >> 3;          // 0..127
  int mB = idx & 7;
  int r2 = idx >> 3;                  // 0..15
  int kh = r2 & 1;
  int p = r2 >> 1;                    // 0..7
  int n = cnt[e];
  int m0 = mB * 128;
  if (m0 >= n) return;
  int sb = base[e];
  int tid = threadIdx.x;
  int wv = tid >> 6, lane = tid & 63, lr = lane & 15, lg = lane >> 4;
  const int kbase = kh * 1792;

  __shared__ __align__(16) char smem2[32768];
  char* sB0 = smem2;                  // 16KB (32 rows x 512B)
  char* sB1 = smem2 + 16384;

  // B staging: wave wv stages rows wv*8 + 2j + (lane>>5), chunk pre-swizzled
  int swzv = ((wv & 1) << 2) | (wv >> 1);
  int bchunk = (lane & 31) ^ swzv;
  const float* Bsrc = wd + (size_t)e * F * H
                    + (size_t)(kbase + wv * 8 + (lane >> 5)) * H + p * 128 + bchunk * 4;

  int swzl = ((lg & 1) << 2) | (lg >> 1);
  int rb[2];
  #pragma unroll
  for (int cf = 0; cf < 2; ++cf) {
    int col = wv * 32 + cf * 16 + lr;
    rb[cf] = (col * 4) ^ (swzl << 4);
  }
  const int rowbase = lg * 8 * 512;

  const unsigned short* ax[8];
  #pragma unroll
  for (int mf = 0; mf < 8; ++mf) {
    int sl = m0 + mf * 16 + lr; if (sl >= n) sl = n - 1;
    ax[mf] = act + (size_t)(sb + sl) * F + kbase + lg * 8;
  }

  f32x4 acc[8][2];
  #pragma unroll
  for (int mf = 0; mf < 8; ++mf) { acc[mf][0] = (f32x4)0.f; acc[mf][1] = (f32x4)0.f; }

#define ISSUE2(S, buf) { \
    const float* bs_ = Bsrc + (size_t)(S) * 32 * H; \
    _Pragma("unroll") for (int j = 0; j < 4; ++j) \
      gload16(bs_ + (size_t)(2 * j) * H, (buf) + (wv * 8 + 2 * j) * 512); }

  ISSUE2(0, sB0);
  ISSUE2(1, sB1);

  for (int s = 0; s < 56; ++s) {
    char* cB = (s & 1) ? sB1 : sB0;
    if (s < 55) { asm volatile("s_waitcnt vmcnt(4)" ::: "memory"); }
    else        { asm volatile("s_waitcnt vmcnt(0)" ::: "memory"); }
    __builtin_amdgcn_s_barrier();
    asm volatile("" ::: "memory");

    bf16x8 b0 = ldcvt((const float*)(cB + rowbase + rb[0]), 128);
    bf16x8 b1 = ldcvt((const float*)(cB + rowbase + rb[1]), 128);
    #pragma unroll
    for (int mf = 0; mf < 8; ++mf) {
      bf16x8 af = *(const bf16x8*)(ax[mf] + s * 32);
      acc[mf][0] = MFMA16(af, b0, acc[mf][0]);
      acc[mf][1] = MFMA16(af, b1, acc[mf][1]);
    }
    asm volatile("s_waitcnt lgkmcnt(0)" ::: "memory");
    __builtin_amdgcn_s_barrier();
    asm volatile("" ::: "memory");
    if (s + 2 < 56) { ISSUE2(s + 2, cB); }
  }
#undef ISSUE2

  #pragma unroll
  for (int mf = 0; mf < 8; ++mf) {
    #pragma unroll
    for (int cf = 0; cf < 2; ++cf) {
      int col = p * 128 + wv * 32 + cf * 16 + lr;
      #pragma unroll
      for (int r = 0; r < 4; ++r) {
        int sl = m0 + mf * 16 + lg * 4 + r;
        if (sl < n) {
          int slot = sb + sl;
          atomicAdd(&out[(size_t)gtok[slot] * H + col], gws[slot] * acc[mf][cf][r]);
        }
      }
    }
  }
}

extern "C" void kernel_launch(void* const* d_in, const int* in_sizes, int n_in,
                              void* d_out, int out_size, void* d_ws, size_t ws_size,
                              hipStream_t stream)
{
  const float* x   = (const float*)d_in[0];
  const float* gw  = (const float*)d_in[1];
  const float* wgu = (const float*)d_in[2];
  const float* wdn = (const float*)d_in[3];
  float* out = (float*)d_out;
  float* logits = out + (size_t)T * H;

  char* w = (char*)d_ws;
  int*   cnt = (int*)(w);
  int*   bs  = (int*)(w + 32);
  int*   te  = (int*)(w + 64);
  int*   tr  = (int*)(w + 64 + 8192);
  float* tw  = (float*)(w + 64 + 16384);
  int*   gt  = (int*)(w + 64 + 24576);
  float* gwt = (float*)(w + 64 + 32768);
  unsigned short* act = (unsigned short*)(w + 65536);          // 2048 x 3584 bf16 = 14.68 MB
  unsigned short* xb  = (unsigned short*)(w + 14745600);       // 1024 x 1024 bf16 = 2 MB

  hipMemsetAsync(d_out, 0, (size_t)T * H * sizeof(float), stream);
  hipMemsetAsync(cnt, 0, NE * sizeof(int), stream);
  cvtx_k<<<512, 256, 0, stream>>>(x, xb);
  router_k<<<T, 64, 0, stream>>>(x, gw, logits, cnt, te, tr, tw);
  build_k<<<1, 1024, 0, stream>>>(cnt, bs, te, tr, tw, gt, gwt);
  ffn1_k<<<1792, 256, 0, stream>>>(xb, wgu, cnt, bs, gt, act);
  ffn2_k<<<1024, 256, 0, stream>>>(act, wdn, cnt, bs, gt, gwt, out);
}

// Round 12
// 358.096 us; speedup vs baseline: 1.2640x; 1.2640x over previous
//
#include <hip/hip_runtime.h>
#include <hip/hip_bf16.h>
#include <math.h>

#define H 1024
#define F 3584
#define F2 7168
#define NE 8
#define T 1024

typedef __attribute__((ext_vector_type(4))) float f32x4;
typedef __attribute__((ext_vector_type(8))) short bf16x8;
typedef __attribute__((ext_vector_type(4))) unsigned u32x4;

__device__ inline short f2bf(float f) {
  union { float f; unsigned u; } v; v.f = f;
  unsigned r = (v.u + 0x7FFFu + ((v.u >> 16) & 1u)) >> 16;
  return (short)r;
}

__device__ inline unsigned pkbf(float a, float b) {
  unsigned r;
  asm("v_cvt_pk_bf16_f32 %0, %1, %2" : "=v"(r) : "v"(a), "v"(b));
  return r;
}

#define MFMA16(af, bf, c) __builtin_amdgcn_mfma_f32_16x16x32_bf16((af), (bf), (c), 0, 0, 0)

// convert 8 fp32 (registers, constant base index) -> bf16x8; pack order = R10-proven
#define CVT8(dst, arr, o) { union { u32x4 u; bf16x8 h; } cv_; \
    cv_.u[0] = pkbf(arr[(o) + 0], arr[(o) + 1]); \
    cv_.u[1] = pkbf(arr[(o) + 2], arr[(o) + 3]); \
    cv_.u[2] = pkbf(arr[(o) + 4], arr[(o) + 5]); \
    cv_.u[3] = pkbf(arr[(o) + 6], arr[(o) + 7]); \
    dst = cv_.h; }

// ---------------- x -> bf16 prepass ----------------
__global__ __launch_bounds__(256) void cvtx_k(
    const float* __restrict__ x, unsigned short* __restrict__ xb)
{
  int i = (blockIdx.x * 256 + threadIdx.x) * 8;
  f32x4 a = *(const f32x4*)(x + i);
  f32x4 b = *(const f32x4*)(x + i + 4);
  u32x4 o;
  o[0] = pkbf(a[0], a[1]); o[1] = pkbf(a[2], a[3]);
  o[2] = pkbf(b[0], b[1]); o[3] = pkbf(b[2], b[3]);
  *(u32x4*)(xb + i) = o;
}

// ---------------- router: fp64 logits, top-2 ----------------
__global__ __launch_bounds__(64) void router_k(
    const float* __restrict__ x, const float* __restrict__ gw,
    float* __restrict__ logits, int* __restrict__ cnt,
    int* __restrict__ tok_e, int* __restrict__ tok_r, float* __restrict__ tok_w)
{
  int t = blockIdx.x, l = threadIdx.x;
  const float* xr = x + (size_t)t * H;
  double acc[NE];
  #pragma unroll
  for (int e = 0; e < NE; ++e) acc[e] = 0.0;
  for (int j = 0; j < H / 64; ++j) {
    int h = j * 64 + l;
    float xv = xr[h];
    #pragma unroll
    for (int e = 0; e < NE; ++e) acc[e] += (double)xv * (double)gw[e * H + h];
  }
  #pragma unroll
  for (int off = 32; off >= 1; off >>= 1) {
    #pragma unroll
    for (int e = 0; e < NE; ++e) acc[e] += __shfl_down(acc[e], off, 64);
  }
  if (l == 0) {
    float lg[NE];
    #pragma unroll
    for (int e = 0; e < NE; ++e) { lg[e] = (float)acc[e]; logits[t * NE + e] = lg[e]; }
    int i0 = 0;
    for (int e = 1; e < NE; ++e) if (lg[e] > lg[i0]) i0 = e;
    int i1 = (i0 == 0) ? 1 : 0;
    for (int e = 0; e < NE; ++e) if (e != i0 && lg[e] > lg[i1]) i1 = e;
    float w0 = 1.f / (1.f + expf(lg[i1] - lg[i0]));
    float w1 = 1.f / (1.f + expf(lg[i0] - lg[i1]));
    int r0 = atomicAdd(&cnt[i0], 1);
    int r1 = atomicAdd(&cnt[i1], 1);
    tok_e[2 * t] = i0;     tok_r[2 * t] = r0;     tok_w[2 * t] = w0;
    tok_e[2 * t + 1] = i1; tok_r[2 * t + 1] = r1; tok_w[2 * t + 1] = w1;
  }
}

// ---------------- scan + gather list ----------------
__global__ __launch_bounds__(1024) void build_k(
    const int* __restrict__ cnt, int* __restrict__ base,
    const int* __restrict__ tok_e, const int* __restrict__ tok_r,
    const float* __restrict__ tok_w, int* __restrict__ gtok, float* __restrict__ gws)
{
  __shared__ int sb[NE];
  if (threadIdx.x == 0) {
    int s = 0;
    for (int e = 0; e < NE; ++e) { sb[e] = s; base[e] = s; s += cnt[e]; }
  }
  __syncthreads();
  int t = threadIdx.x;
  #pragma unroll
  for (int k = 0; k < 2; ++k) {
    int e = tok_e[2 * t + k];
    int slot = sb[e] + tok_r[2 * t + k];
    gtok[slot] = t;
    gws[slot] = tok_w[2 * t + k];
  }
}

// ---------------- ffn1: NO-LDS register GEMM, M=64, N=256 (128g+128u), BK=32 ----------------
// R10-proven addressing; 1-phase named-register prefetch of B (32 dwords) and A (4 b128).
__global__ __launch_bounds__(256, 2) void ffn1_k(
    const unsigned short* __restrict__ xb, const float* __restrict__ wgu,
    const int* __restrict__ cnt, const int* __restrict__ base,
    const int* __restrict__ gtok, unsigned short* __restrict__ act)
{
  // 3584 blocks = 8 XCD * 448 (one expert per XCD), mB fastest for L2 dedup
  int wg = (blockIdx.x & 7) * 448 + (blockIdx.x >> 3);
  int mB = wg & 15;
  int rest = wg >> 4;                 // 0..223
  int e = rest / 28, p = rest % 28;
  int n = cnt[e];
  int m0 = mB * 64;
  if (m0 >= n) return;
  int sb = base[e];
  int tid = threadIdx.x;
  int wv = tid >> 6, lane = tid & 63, lr = lane & 15, lg = lane >> 4;

  // B per-lane base: col = p*128 + wv*32 + lr, k = lg*8; frags +0, +16, +F, +F+16
  const float* Bq = wgu + (size_t)e * H * F2 + (size_t)(lg * 8) * F2 + p * 128 + wv * 32 + lr;

  // A per-lane row pointers (token gather, clamped), direct-global bf16
  const unsigned short* ax[4];
  #pragma unroll
  for (int mf = 0; mf < 4; ++mf) {
    int sl = m0 + mf * 16 + lr; if (sl >= n) sl = n - 1;
    ax[mf] = xb + (size_t)gtok[sb + sl] * H + lg * 8;
  }

  f32x4 acc[4][4];
  #pragma unroll
  for (int mf = 0; mf < 4; ++mf)
    #pragma unroll
    for (int cf = 0; cf < 4; ++cf) acc[mf][cf] = (f32x4)0.f;

  float bc[32], bn[32];
  bf16x8 ac[4], an[4];

#define LOADB1(dst, S) { const float* bp_ = Bq + (size_t)(S) * 32 * F2; \
    _Pragma("unroll") for (int j = 0; j < 8; ++j) { \
      dst[j]      = bp_[(size_t)j * F2]; \
      dst[8 + j]  = bp_[(size_t)j * F2 + 16]; \
      dst[16 + j] = bp_[(size_t)j * F2 + F]; \
      dst[24 + j] = bp_[(size_t)j * F2 + F + 16]; } }
#define LOADA1(dst, S) { _Pragma("unroll") for (int mf = 0; mf < 4; ++mf) \
      dst[mf] = *(const bf16x8*)(ax[mf] + (S) * 32); }

  LOADB1(bc, 0);
  LOADA1(ac, 0);

  for (int s = 0; s < 32; ++s) {
    if (s < 31) { LOADB1(bn, s + 1); LOADA1(an, s + 1); }
    bf16x8 b0, b1, b2, b3;
    CVT8(b0, bc, 0); CVT8(b1, bc, 8); CVT8(b2, bc, 16); CVT8(b3, bc, 24);
    #pragma unroll
    for (int mf = 0; mf < 4; ++mf) {
      acc[mf][0] = MFMA16(ac[mf], b0, acc[mf][0]);
      acc[mf][1] = MFMA16(ac[mf], b1, acc[mf][1]);
      acc[mf][2] = MFMA16(ac[mf], b2, acc[mf][2]);
      acc[mf][3] = MFMA16(ac[mf], b3, acc[mf][3]);
    }
    if (s < 31) {
      #pragma unroll
      for (int i = 0; i < 32; ++i) bc[i] = bn[i];
      #pragma unroll
      for (int mf = 0; mf < 4; ++mf) ac[mf] = an[mf];
    }
  }
#undef LOADB1
#undef LOADA1

  // epilogue: silu(gate)*up; gate cf 0..1, up cf 2..3
  #pragma unroll
  for (int mf = 0; mf < 4; ++mf) {
    #pragma unroll
    for (int g = 0; g < 2; ++g) {
      int fcol = p * 128 + wv * 32 + g * 16 + lr;
      #pragma unroll
      for (int r = 0; r < 4; ++r) {
        int sl = m0 + mf * 16 + lg * 4 + r;
        if (sl < n) {
          float gg = acc[mf][g][r], u = acc[mf][g + 2][r];
          act[(size_t)(sb + sl) * F + fcol] = (unsigned short)f2bf(gg / (1.f + expf(-gg)) * u);
        }
      }
    }
  }
}

// ---------------- ffn2: NO-LDS register GEMM, M=64, N=128, BK=32, K-split x4 ----------------
__global__ __launch_bounds__(256, 2) void ffn2_k(
    const unsigned short* __restrict__ act, const float* __restrict__ wd,
    const int* __restrict__ cnt, const int* __restrict__ base,
    const int* __restrict__ gtok, const float* __restrict__ gws,
    float* __restrict__ out)
{
  // 4096 blocks = 8 XCD * 512 (one expert per XCD): 16 mB * 8 p * 4 kh, mB fastest
  int wg = (blockIdx.x & 7) * 512 + (blockIdx.x >> 3);
  int mB = wg & 15;
  int rest = wg >> 4;                // 0..255
  int p = rest & 7;
  int kh = (rest >> 3) & 3;
  int e = rest >> 5;
  int n = cnt[e];
  int m0 = mB * 64;
  if (m0 >= n) return;
  int sb = base[e];
  int tid = threadIdx.x;
  int wv = tid >> 6, lane = tid & 63, lr = lane & 15, lg = lane >> 4;
  const int kbase = kh * 896;

  const float* Bq = wd + (size_t)e * F * H + (size_t)(kbase + lg * 8) * H + p * 128 + wv * 32 + lr;

  const unsigned short* ax[4];
  #pragma unroll
  for (int mf = 0; mf < 4; ++mf) {
    int sl = m0 + mf * 16 + lr; if (sl >= n) sl = n - 1;
    ax[mf] = act + (size_t)(sb + sl) * F + kbase + lg * 8;
  }

  f32x4 acc[4][2];
  #pragma unroll
  for (int mf = 0; mf < 4; ++mf) { acc[mf][0] = (f32x4)0.f; acc[mf][1] = (f32x4)0.f; }

  float bc[16], bn[16];
  bf16x8 ac[4], an[4];

#define LOADB2(dst, S) { const float* bp_ = Bq + (size_t)(S) * 32 * H; \
    _Pragma("unroll") for (int j = 0; j < 8; ++j) { \
      dst[j]     = bp_[(size_t)j * H]; \
      dst[8 + j] = bp_[(size_t)j * H + 16]; } }
#define LOADA2(dst, S) { _Pragma("unroll") for (int mf = 0; mf < 4; ++mf) \
      dst[mf] = *(const bf16x8*)(ax[mf] + (S) * 32); }

  LOADB2(bc, 0);
  LOADA2(ac, 0);

  for (int s = 0; s < 28; ++s) {
    if (s < 27) { LOADB2(bn, s + 1); LOADA2(an, s + 1); }
    bf16x8 b0, b1;
    CVT8(b0, bc, 0); CVT8(b1, bc, 8);
    #pragma unroll
    for (int mf = 0; mf < 4; ++mf) {
      acc[mf][0] = MFMA16(ac[mf], b0, acc[mf][0]);
      acc[mf][1] = MFMA16(ac[mf], b1, acc[mf][1]);
    }
    if (s < 27) {
      #pragma unroll
      for (int i = 0; i < 16; ++i) bc[i] = bn[i];
      #pragma unroll
      for (int mf = 0; mf < 4; ++mf) ac[mf] = an[mf];
    }
  }
#undef LOADB2
#undef LOADA2

  #pragma unroll
  for (int mf = 0; mf < 4; ++mf) {
    #pragma unroll
    for (int cf = 0; cf < 2; ++cf) {
      int col = p * 128 + wv * 32 + cf * 16 + lr;
      #pragma unroll
      for (int r = 0; r < 4; ++r) {
        int sl = m0 + mf * 16 + lg * 4 + r;
        if (sl < n) {
          int slot = sb + sl;
          atomicAdd(&out[(size_t)gtok[slot] * H + col], gws[slot] * acc[mf][cf][r]);
        }
      }
    }
  }
}

extern "C" void kernel_launch(void* const* d_in, const int* in_sizes, int n_in,
                              void* d_out, int out_size, void* d_ws, size_t ws_size,
                              hipStream_t stream)
{
  const float* x   = (const float*)d_in[0];
  const float* gw  = (const float*)d_in[1];
  const float* wgu = (const float*)d_in[2];
  const float* wdn = (const float*)d_in[3];
  float* out = (float*)d_out;
  float* logits = out + (size_t)T * H;

  char* w = (char*)d_ws;
  int*   cnt = (int*)(w);
  int*   bs  = (int*)(w + 32);
  int*   te  = (int*)(w + 64);
  int*   tr  = (int*)(w + 64 + 8192);
  float* tw  = (float*)(w + 64 + 16384);
  int*   gt  = (int*)(w + 64 + 24576);
  float* gwt = (float*)(w + 64 + 32768);
  unsigned short* act = (unsigned short*)(w + 65536);          // 2048 x 3584 bf16 = 14.68 MB
  unsigned short* xb  = (unsigned short*)(w + 14745600);       // 1024 x 1024 bf16 = 2 MB

  hipMemsetAsync(d_out, 0, (size_t)T * H * sizeof(float), stream);
  hipMemsetAsync(cnt, 0, NE * sizeof(int), stream);
  cvtx_k<<<512, 256, 0, stream>>>(x, xb);
  router_k<<<T, 64, 0, stream>>>(x, gw, logits, cnt, te, tr, tw);
  build_k<<<1, 1024, 0, stream>>>(cnt, bs, te, tr, tw, gt, gwt);
  ffn1_k<<<3584, 256, 0, stream>>>(xb, wgu, cnt, bs, gt, act);
  ffn2_k<<<4096, 256, 0, stream>>>(act, wdn, cnt, bs, gt, gwt, out);
}